// Round 10
// baseline (15.506 us; speedup 1.0000x reference)
//
#include <hip/hip_runtime.h>

constexpr int N = 512;
constexpr int D = 128;
constexpr int A = 2;             // anchors per block
constexpr int NBLK = N / A;      // 256 blocks = 1 per CU
constexpr float MARGIN = 1.0f;
constexpr float EPS_T = 1e-16f;

// Main: 2 anchors/block, 256 blocks, 1024 threads (16 waves/CU = 4/SIMD,
// double R9's TLP for latency hiding; half the per-thread serial work).
//  P1: 4 passes; 8 lanes/row; row r = p*128 + (tid>>3); lane sub reads float4
//      chunks {sub,sub+8,sub+16,sub+24} (coalesced). Same 8-lane shfl_xor tree
//      as R9 -> bitwise-identical distances.
//  P2: 16 waves compact in parallel: threads 0-511 anchor 0, 512-1023 anchor 1
//      (ballot -> per-wave counts -> scan -> write; ascending-j preserved).
//  P3: thread handles ONE anchor (g = tid>>9), k = tid&511.
//  P4: 16-wave fixed-tree f64 reduction -> per-block (sum, npos, ntrip).
// Final: one block, 256 threads, reduces 256 triples -> two scalars.
__global__ __launch_bounds__(1024, 4) void triplet_main_k(
    const float* __restrict__ emb, const int* __restrict__ labels,
    double* __restrict__ partial)
{
    __shared__ float  drow[A][N];
    __shared__ float  posd[A][N];
    __shared__ int    cnt[A][8];
    __shared__ int    npos_s[A];
    __shared__ double red[48];   // [0..15]=sum, [16..31]=npos, [32..47]=ntrip

    const int i0   = blockIdx.x * A;
    const int tid  = threadIdx.x;
    const int lane = tid & 63;
    const int wid  = tid >> 6;       // 0..15
    const int sub  = tid & 7;

    // anchors -> registers (8-lane broadcast loads, L1/L2-hot)
    const float4* ea0 = reinterpret_cast<const float4*>(emb + (size_t)i0 * D);
    const float4* ea1 = reinterpret_cast<const float4*>(emb + (size_t)(i0 + 1) * D);
    const float4 a00 = ea0[sub], a01 = ea0[sub + 8], a02 = ea0[sub + 16], a03 = ea0[sub + 24];
    const float4 a10 = ea1[sub], a11 = ea1[sub + 8], a12 = ea1[sub + 16], a13 = ea1[sub + 24];

    const int lk  = labels[tid & (N - 1)];   // this thread's k-label (k = tid&511)
    const int li0 = labels[i0];              // uniform broadcasts
    const int li1 = labels[i0 + 1];

    // ---- P1: coalesced distance rows, 4 passes, both anchors ----
    #pragma unroll
    for (int p = 0; p < 4; ++p) {
        const int r = p * 128 + (tid >> 3);
        const float4* er = reinterpret_cast<const float4*>(emb + (size_t)r * D);
        const float4 v0 = er[sub], v1 = er[sub + 8], v2 = er[sub + 16], v3 = er[sub + 24];
        float sq0 = 0.f, sq1 = 0.f;
        {
            float d0 = a00.x - v0.x, d1 = a00.y - v0.y, d2 = a00.z - v0.z, d3 = a00.w - v0.w;
            sq0 += d0 * d0 + d1 * d1 + d2 * d2 + d3 * d3;
            d0 = a01.x - v1.x; d1 = a01.y - v1.y; d2 = a01.z - v1.z; d3 = a01.w - v1.w;
            sq0 += d0 * d0 + d1 * d1 + d2 * d2 + d3 * d3;
            d0 = a02.x - v2.x; d1 = a02.y - v2.y; d2 = a02.z - v2.z; d3 = a02.w - v2.w;
            sq0 += d0 * d0 + d1 * d1 + d2 * d2 + d3 * d3;
            d0 = a03.x - v3.x; d1 = a03.y - v3.y; d2 = a03.z - v3.z; d3 = a03.w - v3.w;
            sq0 += d0 * d0 + d1 * d1 + d2 * d2 + d3 * d3;
        }
        {
            float d0 = a10.x - v0.x, d1 = a10.y - v0.y, d2 = a10.z - v0.z, d3 = a10.w - v0.w;
            sq1 += d0 * d0 + d1 * d1 + d2 * d2 + d3 * d3;
            d0 = a11.x - v1.x; d1 = a11.y - v1.y; d2 = a11.z - v1.z; d3 = a11.w - v1.w;
            sq1 += d0 * d0 + d1 * d1 + d2 * d2 + d3 * d3;
            d0 = a12.x - v2.x; d1 = a12.y - v2.y; d2 = a12.z - v2.z; d3 = a12.w - v2.w;
            sq1 += d0 * d0 + d1 * d1 + d2 * d2 + d3 * d3;
            d0 = a13.x - v3.x; d1 = a13.y - v3.y; d2 = a13.z - v3.z; d3 = a13.w - v3.w;
            sq1 += d0 * d0 + d1 * d1 + d2 * d2 + d3 * d3;
        }
        sq0 += __shfl_xor(sq0, 1); sq1 += __shfl_xor(sq1, 1);
        sq0 += __shfl_xor(sq0, 2); sq1 += __shfl_xor(sq1, 2);
        sq0 += __shfl_xor(sq0, 4); sq1 += __shfl_xor(sq1, 4);
        if (sub == 0) {
            drow[0][r] = (sq0 > 0.f) ? sqrtf(sq0) : 0.f;   // safe sqrt
            drow[1][r] = (sq1 > 0.f) ? sqrtf(sq1) : 0.f;
        }
    }
    __syncthreads();

    // ---- P2: parallel compaction; group g handles anchor g ----
    const int g   = tid >> 9;            // 0 or 1 (aligned to wave boundary)
    const int w8  = wid & 7;             // wave-in-group 0..7
    const int j   = w8 * 64 + lane;      // candidate index owned by this thread
    const int lig = g ? li1 : li0;
    const bool pr = (labels[j] == lig) && (j != i0 + g);
    const unsigned long long m = __ballot(pr);
    if (lane == 0) cnt[g][w8] = __popcll(m);
    __syncthreads();
    int base = 0;
    #pragma unroll
    for (int w = 0; w < 8; ++w) base += (w < w8) ? cnt[g][w] : 0;
    if (pr) posd[g][base + __popcll(m & ((1ull << lane) - 1ull))] = drow[g][j];
    if ((tid & (N - 1)) == 0) {          // tid 0 and 512
        int t = 0;
        #pragma unroll
        for (int w = 0; w < 8; ++w) t += cnt[g][w];
        npos_s[g] = t;
    }
    __syncthreads();

    // ---- P3: hinge accumulation; one anchor per thread ----
    const int   k   = tid & (N - 1);
    const float dik = drow[g][k];
    double sum = 0.0;
    int np_i = 0, nt_i = 0;
    if (lk != lig) {
        const int npos = npos_s[g];
        for (int p = 0; p < npos; ++p) {
            const float t = (posd[g][p] - dik) + MARGIN;  // reference op order
            if (t > EPS_T) { sum += (double)t; ++np_i; }
        }
        nt_i = npos;
    }

    // ---- P4: fixed-tree reduction (16 waves) ----
    double s = sum, p = (double)np_i, t = (double)nt_i;
    #pragma unroll
    for (int off = 32; off > 0; off >>= 1) {
        s += __shfl_down(s, off);
        p += __shfl_down(p, off);
        t += __shfl_down(t, off);
    }
    if (lane == 0) { red[wid] = s; red[16 + wid] = p; red[32 + wid] = t; }
    __syncthreads();
    if (tid == 0) {
        double S = 0.0, P = 0.0, T = 0.0;
        #pragma unroll
        for (int w = 0; w < 16; ++w) { S += red[w]; P += red[16 + w]; T += red[32 + w]; }
        partial[blockIdx.x]            = S;
        partial[NBLK + blockIdx.x]     = P;
        partial[2 * NBLK + blockIdx.x] = T;
    }
}

__global__ __launch_bounds__(256) void triplet_final_k(
    const double* __restrict__ partial, float* __restrict__ out)
{
    __shared__ double red[12];
    const int tid  = threadIdx.x;
    const int lane = tid & 63;
    const int wid  = tid >> 6;
    double a = partial[tid];
    double b = partial[NBLK + tid];
    double c = partial[2 * NBLK + tid];
    #pragma unroll
    for (int off = 32; off > 0; off >>= 1) {
        a += __shfl_down(a, off);
        b += __shfl_down(b, off);
        c += __shfl_down(c, off);
    }
    if (lane == 0) { red[wid] = a; red[4 + wid] = b; red[8 + wid] = c; }
    __syncthreads();
    if (tid == 0) {
        const double S = red[0] + red[1] + red[2]  + red[3];
        const double P = red[4] + red[5] + red[6]  + red[7];
        const double T = red[8] + red[9] + red[10] + red[11];
        out[0] = (float)(S / (P + 1e-16));  // loss
        out[1] = (float)(P / (T + 1e-16));  // fraction_positive
    }
}

extern "C" void kernel_launch(void* const* d_in, const int* in_sizes, int n_in,
                              void* d_out, int out_size, void* d_ws, size_t ws_size,
                              hipStream_t stream) {
    const float* emb   = (const float*)d_in[0];   // [512,128] f32
    const int*   lab   = (const int*)d_in[1];     // [512] i32
    float*       out   = (float*)d_out;           // [2] f32: loss, fraction_positive
    double*      parts = (double*)d_ws;           // 3*NBLK doubles = 6 KB

    triplet_main_k<<<NBLK, 1024, 0, stream>>>(emb, lab, parts);
    triplet_final_k<<<1, 256, 0, stream>>>(parts, out);
}